// Round 5
// baseline (662.911 us; speedup 1.0000x reference)
//
#include <hip/hip_runtime.h>
#include <stdint.h>

#define NSEQ 256
#define LRES 384
#define NH   8
#define NL   (NSEQ*LRES)              // 98304 msa rows
#define SCALE 0.17677669529663687f    // 1/sqrt(32)

typedef unsigned short u16;
typedef unsigned int   u32;
typedef short bf16x8 __attribute__((ext_vector_type(8)));
typedef float f32x4  __attribute__((ext_vector_type(4)));

// ---------- bf16 helpers ----------
__device__ __forceinline__ u16 f2bf(float f) {
    u32 x = __float_as_uint(f);
    return (u16)((x + 0x7fffu + ((x >> 16) & 1u)) >> 16);
}
__device__ __forceinline__ u32 pack2(float a, float b) {
    u32 xa = __float_as_uint(a);
    u32 xb = __float_as_uint(b);
    xa = (xa + 0x7fffu + ((xa >> 16) & 1u)) >> 16;
    xb = ((xb + 0x7fffu + ((xb >> 16) & 1u)) >> 16) << 16;
    return xa | xb;
}
__device__ __forceinline__ uint4 pack8(const float f[8]) {
    uint4 r;
    r.x = pack2(f[0], f[1]); r.y = pack2(f[2], f[3]);
    r.z = pack2(f[4], f[5]); r.w = pack2(f[6], f[7]);
    return r;
}
__device__ __forceinline__ void unpack2(u32 u, float& f0, float& f1) {
    f0 = __uint_as_float((u & 0xffffu) << 16);
    f1 = __uint_as_float(u & 0xffff0000u);
}
__device__ __forceinline__ void unpack8(uint4 p, float f[8]) {
    unpack2(p.x, f[0], f[1]);
    unpack2(p.y, f[2], f[3]);
    unpack2(p.z, f[4], f[5]);
    unpack2(p.w, f[6], f[7]);
}

// ---------- wave-64 reductions ----------
__device__ __forceinline__ float wred_sum(float v) {
#pragma unroll
    for (int o = 32; o > 0; o >>= 1) v += __shfl_xor(v, o, 64);
    return v;
}
__device__ __forceinline__ float wred_max(float v) {
#pragma unroll
    for (int o = 32; o > 0; o >>= 1) v = fmaxf(v, __shfl_xor(v, o, 64));
    return v;
}

// =====================================================================
// K0: fused LN of msa -> bf16 lnA (98304x256), + per-row stats out.
// =====================================================================
__global__ __launch_bounds__(256) void ln_msa_k(
    const float* __restrict__ x, const float* __restrict__ g,
    const float* __restrict__ b, u16* __restrict__ lnA,
    float* __restrict__ stats)
{
    const int lane = threadIdx.x & 63;
    const int row = blockIdx.x * 4 + (threadIdx.x >> 6);
    const size_t base = (size_t)row * 256 + lane * 4;
    float4 v = *(const float4*)(x + base);
    float s  = wred_sum(v.x + v.y + v.z + v.w);
    float sq = wred_sum(v.x*v.x + v.y*v.y + v.z*v.z + v.w*v.w);
    const float mu  = s * (1.f / 256.f);
    const float var = sq * (1.f / 256.f) - mu * mu;
    const float rs  = rsqrtf(var + 1e-5f);
    if (lane == 0) {
        stats[(size_t)row * 2]     = mu;
        stats[(size_t)row * 2 + 1] = rs;
    }
    float4 gg = *(const float4*)(g + lane * 4);
    float4 bb = *(const float4*)(b + lane * 4);
    float f0 = (v.x - mu) * rs * gg.x + bb.x;
    float f1 = (v.y - mu) * rs * gg.y + bb.y;
    float f2 = (v.z - mu) * rs * gg.z + bb.z;
    float f3 = (v.w - mu) * rs * gg.w + bb.w;
    uint2 pk;
    pk.x = pack2(f0, f1);
    pk.y = pack2(f2, f3);
    *(uint2*)(lnA + base) = pk;
}

// =====================================================================
// K0b: transpose+convert 6 weight matrices (256x256 fp32, [k][c]) into
// WtAll (6 x 256 x 256 bf16, [c][k]). 64x64 LDS-tiled. 96 blocks.
// =====================================================================
__global__ __launch_bounds__(256) void wconv_k(
    const float* __restrict__ W0, const float* __restrict__ W1,
    const float* __restrict__ W2, const float* __restrict__ W3,
    const float* __restrict__ W4, const float* __restrict__ W5,
    u16* __restrict__ outAll)
{
    const float* Wsrc[6] = {W0, W1, W2, W3, W4, W5};
    const int widx = blockIdx.x >> 4;
    const int tile = blockIdx.x & 15;
    const int kt = tile >> 2, ct = tile & 3;
    const float* W = Wsrc[widx];
    __shared__ float ts[64][65];
    const int r  = threadIdx.x >> 2;     // 0..63
    const int cg = threadIdx.x & 3;      // 16-col group
#pragma unroll
    for (int jj = 0; jj < 4; ++jj) {
        float4 v = *(const float4*)(W + (size_t)(kt * 64 + r) * 256
                                      + ct * 64 + cg * 16 + jj * 4);
        ts[r][cg * 16 + jj * 4 + 0] = v.x;
        ts[r][cg * 16 + jj * 4 + 1] = v.y;
        ts[r][cg * 16 + jj * 4 + 2] = v.z;
        ts[r][cg * 16 + jj * 4 + 3] = v.w;
    }
    __syncthreads();
    float lo[8], hi[8];
#pragma unroll
    for (int j = 0; j < 8; ++j) lo[j] = ts[cg * 16 + j][r];
#pragma unroll
    for (int j = 0; j < 8; ++j) hi[j] = ts[cg * 16 + 8 + j][r];
    u16* o = outAll + (size_t)widx * 65536 + (size_t)(ct * 64 + r) * 256
           + kt * 64 + cg * 16;
    *(uint4*)(o)     = pack8(lo);
    *(uint4*)(o + 8) = pack8(hi);
}

// =====================================================================
// K0c: fold ln_pair_g into Wb -> Wp[c][h] = g_c*Wb[c][h] (fp32), and
// AB[0..7]=A[h]=sum g_c Wb[c][h], AB[8..15]=B[h]=sum b_c Wb[c][h].
// =====================================================================
__global__ __launch_bounds__(128) void wbprep_k(
    const float* __restrict__ g, const float* __restrict__ b,
    const float* __restrict__ Wb, float* __restrict__ Wp,
    float* __restrict__ AB)
{
    __shared__ float ps[128][8];
    __shared__ float pb[128][8];
    const int c = threadIdx.x;
    const float gc = g[c], bc = b[c];
    float4 w0 = *(const float4*)(Wb + (size_t)c * 8);
    float4 w1 = *(const float4*)(Wb + (size_t)c * 8 + 4);
    const float wraw[8] = {w0.x, w0.y, w0.z, w0.w, w1.x, w1.y, w1.z, w1.w};
    float wp[8];
#pragma unroll
    for (int h = 0; h < 8; ++h) {
        wp[h] = wraw[h] * gc;
        ps[c][h] = wp[h];
        pb[c][h] = wraw[h] * bc;
    }
    *(float4*)(Wp + (size_t)c * 8)     = make_float4(wp[0], wp[1], wp[2], wp[3]);
    *(float4*)(Wp + (size_t)c * 8 + 4) = make_float4(wp[4], wp[5], wp[6], wp[7]);
    __syncthreads();
    if (c < 8) {
        float a = 0.f;
        for (int j = 0; j < 128; ++j) a += ps[j][c];
        AB[c] = a;
    } else if (c < 16) {
        const int h = c - 8;
        float a = 0.f;
        for (int j = 0; j < 128; ++j) a += pb[j][h];
        AB[8 + h] = a;
    }
}

// =====================================================================
// K1 (legacy fp32 path, QSW only): qsw = (LN(msa[0]) @ W + b) * SCALE.
// =====================================================================
__global__ __launch_bounds__(256) void gemm_ln_k(
    const void* __restrict__ Av, int a_bf16,
    const float* __restrict__ stats,
    const float* __restrict__ lng, const float* __restrict__ lnb,
    const float* __restrict__ W, const float* __restrict__ bias,
    void* __restrict__ out, const float* __restrict__ seqw, int mode)
{
    __shared__ float As_t[32][68];   // [k][row]
    __shared__ float Ws[32][132];    // [k][col]
    __shared__ float gs[256], bs[256];
    const int tid = threadIdx.x;
    const int bx = blockIdx.y;       // column half
    const int by = blockIdx.x;       // row tile
    const int tx = tid & 15, ty = tid >> 4;
    const int ar = tid >> 2, acg = tid & 3;
    const int wr = tid >> 3, wcg = tid & 7;
    const bool do_ln = (stats != nullptr);

    if (do_ln) { gs[tid] = lng[tid]; bs[tid] = lnb[tid]; }
    __syncthreads();

    const int arow_idx = by * 64 + ar;
    float mu = 0.f, rsg = 0.f;
    if (do_ln) {
        mu  = stats[(size_t)arow_idx * 2];
        rsg = stats[(size_t)arow_idx * 2 + 1];
    }

    float acc[4][8];
#pragma unroll
    for (int i = 0; i < 4; ++i)
#pragma unroll
        for (int j = 0; j < 8; ++j) acc[i][j] = 0.f;

    const size_t arow = (size_t)arow_idx * 256 + acg * 8;

    for (int kk = 0; kk < 256; kk += 32) {
        float af[8];
        if (a_bf16) {
            uint4 a8 = *(const uint4*)((const u16*)Av + arow + kk);
            unpack8(a8, af);
        } else {
            float4 x0 = *(const float4*)((const float*)Av + arow + kk);
            float4 x1 = *(const float4*)((const float*)Av + arow + kk + 4);
            af[0] = x0.x; af[1] = x0.y; af[2] = x0.z; af[3] = x0.w;
            af[4] = x1.x; af[5] = x1.y; af[6] = x1.z; af[7] = x1.w;
        }
        const float* wrow = W + (size_t)(kk + wr) * 256 + bx * 128 + wcg * 16;
        float4 w0 = *(const float4*)(wrow);
        float4 w1 = *(const float4*)(wrow + 4);
        float4 w2 = *(const float4*)(wrow + 8);
        float4 w3 = *(const float4*)(wrow + 12);
        if (do_ln) {
#pragma unroll
            for (int j = 0; j < 8; ++j) {
                const int k = kk + acg * 8 + j;
                af[j] = (af[j] - mu) * rsg * gs[k] + bs[k];
            }
        }
        __syncthreads();
#pragma unroll
        for (int j = 0; j < 8; ++j) As_t[acg * 8 + j][ar] = af[j];
        float* wsrow = &Ws[wr][wcg * 16];
        *(float4*)(wsrow)      = w0;
        *(float4*)(wsrow + 4)  = w1;
        *(float4*)(wsrow + 8)  = w2;
        *(float4*)(wsrow + 12) = w3;
        __syncthreads();
#pragma unroll 8
        for (int k = 0; k < 32; ++k) {
            const float4 a  = *(const float4*)&As_t[k][ty * 4];
            const float4 b0 = *(const float4*)&Ws[k][tx * 8];
            const float4 b1 = *(const float4*)&Ws[k][tx * 8 + 4];
            const float av[4] = {a.x, a.y, a.z, a.w};
            const float bv[8] = {b0.x, b0.y, b0.z, b0.w, b1.x, b1.y, b1.z, b1.w};
#pragma unroll
            for (int i = 0; i < 4; ++i)
#pragma unroll
                for (int j = 0; j < 8; ++j)
                    acc[i][j] = fmaf(av[i], bv[j], acc[i][j]);
        }
    }

    const int gc0 = bx * 128 + tx * 8;
    float bias8[8];
#pragma unroll
    for (int j = 0; j < 8; ++j) bias8[j] = bias[gc0 + j];

    float* o = (float*)out;
#pragma unroll
    for (int i = 0; i < 4; ++i) {
        const size_t gr = (size_t)by * 64 + ty * 4 + i;
#pragma unroll
        for (int j = 0; j < 8; ++j)
            o[gr * 256 + gc0 + j] = (acc[i][j] + bias8[j]) * SCALE;
    }
}

// =====================================================================
// K3: softmax over n (stride 3072) per (i,h) column. Wave per column.
// =====================================================================
__global__ __launch_bounds__(256) void softmax_n_k(float* __restrict__ swl)
{
    const int col = blockIdx.x * 4 + (threadIdx.x >> 6);  // i*8+h
    const int lane = threadIdx.x & 63;
    float* base = swl + col;
    float v[4];
#pragma unroll
    for (int t = 0; t < 4; ++t) v[t] = base[(size_t)(lane * 4 + t) * 3072];
    float mx = wred_max(fmaxf(fmaxf(v[0], v[1]), fmaxf(v[2], v[3])));
    float e[4], s = 0.f;
#pragma unroll
    for (int t = 0; t < 4; ++t) { e[t] = __expf(v[t] - mx); s += e[t]; }
    s = wred_sum(s);
    const float inv = 1.f / s;
#pragma unroll
    for (int t = 0; t < 4; ++t) base[(size_t)(lane * 4 + t) * 3072] = e[t] * inv;
}

// =====================================================================
// K4: biasH[(i*384+j)*8+h] = rs*dot(x, Wp[:,h]) - rs*mu*A[h] + B[h].
// 8 pairs/wave; XOR-aligned head accumulation.
// =====================================================================
__global__ __launch_bounds__(256) void pair_bias_k(
    const float* __restrict__ pairX, const float* __restrict__ Wp,
    const float* __restrict__ AB, float* __restrict__ biasH)
{
    __shared__ float ws[128][8];
    __shared__ float As[8], Bs[8];
    const int tid = threadIdx.x;
    {
        float4 w4 = *(const float4*)(Wp + tid * 4);
        *(float4*)(&ws[tid >> 1][(tid & 1) * 4]) = w4;
    }
    if (tid < 8)       As[tid] = AB[tid];
    else if (tid < 16) Bs[tid - 8] = AB[tid];
    __syncthreads();

    const int lane = tid & 63;
    const int p  = lane >> 3;
    const int cg = lane & 7;
    const size_t pb = (size_t)blockIdx.x * 32 + (tid >> 6) * 8 + p;
    const float* src = pairX + pb * 128 + cg * 16;
    float x[16];
    *(float4*)(x)      = *(const float4*)(src);
    *(float4*)(x + 4)  = *(const float4*)(src + 4);
    *(float4*)(x + 8)  = *(const float4*)(src + 8);
    *(float4*)(x + 12) = *(const float4*)(src + 12);

    float s = 0.f, sq = 0.f;
#pragma unroll
    for (int j = 0; j < 16; ++j) { s += x[j]; sq += x[j] * x[j]; }
#pragma unroll
    for (int o = 1; o <= 4; o <<= 1) {
        s  += __shfl_xor(s, o, 64);
        sq += __shfl_xor(sq, o, 64);
    }
    const float mu  = s * (1.f / 128.f);
    const float var = sq * (1.f / 128.f) - mu * mu;
    const float rs  = rsqrtf(var + 1e-5f);

    float acc[8];
#pragma unroll
    for (int hh = 0; hh < 8; ++hh) {
        const int h = hh ^ cg;
        float a = 0.f;
#pragma unroll
        for (int j = 0; j < 16; ++j) a += x[j] * ws[cg * 16 + j][h];
        acc[hh] = a;
    }
#pragma unroll
    for (int o = 1; o <= 4; o <<= 1) {
        float nv[8];
#pragma unroll
        for (int hh = 0; hh < 8; ++hh)
            nv[hh] = acc[hh] + __shfl_xor(acc[hh ^ o], o, 64);
#pragma unroll
        for (int hh = 0; hh < 8; ++hh) acc[hh] = nv[hh];
    }
    const float res = rs * acc[0] - rs * mu * As[cg] + Bs[cg];
    biasH[pb * 8 + cg] = res;
}

// =====================================================================
// MFMA tile helpers: [128 rows][64 k] bf16 tile in LDS, XOR-swizzled.
// =====================================================================
__device__ __forceinline__ void stage128x64(
    const u16* __restrict__ src, size_t rowStride, u16* lds, int tid)
{
    const int row   = tid >> 1;          // 128 rows, 2 threads each
    const int cbase = (tid & 1) * 4;     // chunks {0..3} or {4..7}
#pragma unroll
    for (int ch = 0; ch < 4; ++ch) {
        const int cc = cbase + ch;
        const uint4 v = *(const uint4*)(src + (size_t)row * rowStride + cc * 8);
        *(uint4*)(lds + row * 64 + ((cc ^ (row & 7)) * 8)) = v;
    }
}

__device__ __forceinline__ bf16x8 frag_read(const u16* lds, int row, int kchunk)
{
    return *(const bf16x8*)(lds + row * 64 + ((kchunk ^ (row & 7)) * 8));
}

// Shared MFMA core: 128x128 C-tile, K=256 (A and Wt both [row][256] bf16).
__device__ __forceinline__ void proj_core(
    const u16* __restrict__ Ab, const u16* __restrict__ Wb,
    u16* tA, u16* tW, int tid, int mrow, int nrow, int g, f32x4 acc[4][4])
{
#pragma unroll
    for (int m = 0; m < 4; ++m)
#pragma unroll
        for (int n = 0; n < 4; ++n) {
            f32x4 z = {0.f, 0.f, 0.f, 0.f};
            acc[m][n] = z;
        }
    for (int k0 = 0; k0 < 256; k0 += 64) {
        stage128x64(Ab + k0, 256, tA, tid);
        stage128x64(Wb + k0, 256, tW, tid);
        __syncthreads();
#pragma unroll
        for (int ks = 0; ks < 2; ++ks) {
            bf16x8 wf[4], af[4];
#pragma unroll
            for (int m = 0; m < 4; ++m) wf[m] = frag_read(tW, mrow + m * 16, ks * 4 + g);
#pragma unroll
            for (int n = 0; n < 4; ++n) af[n] = frag_read(tA, nrow + n * 16, ks * 4 + g);
#pragma unroll
            for (int m = 0; m < 4; ++m)
#pragma unroll
                for (int n = 0; n < 4; ++n)
                    acc[m][n] = __builtin_amdgcn_mfma_f32_16x16x32_bf16(
                        wf[m], af[n], acc[m][n], 0, 0, 0);
        }
        __syncthreads();
    }
}

// =====================================================================
// K1'a (MFMA, fused x4): per block row/col tile, run 4 projections:
//  slot0: KSW -> fused swl dot (never materializes ksw)
//  slot1: KT  -> kT bf16 [h][i][n*32+d], x SCALE
//  slot2: VT  -> vTT bf16 [h][n*32+d][i]
//  slot3: GATE-> sigmoid(.+bg) bf16 [r][c]
// =====================================================================
__global__ __launch_bounds__(256) void proj4_mfma(
    const u16* __restrict__ A,
    const u16* __restrict__ Wt_ksw, const u16* __restrict__ Wt_k,
    const u16* __restrict__ Wt_v,   const u16* __restrict__ Wt_g,
    const float* __restrict__ bias_ksw, const float* __restrict__ bias_g,
    const float* __restrict__ qsw,
    float* __restrict__ swl, u16* __restrict__ outKT,
    u16* __restrict__ outVT, u16* __restrict__ outGATE)
{
    __shared__ u16 tA[128 * 64];
    __shared__ u16 tW[128 * 64];

    int wg = (blockIdx.x & 7) * 192 + (blockIdx.x >> 3);
    const int rowTile = wg >> 1;       // 0..767
    const int colTile = wg & 1;        // 0..1

    const int tid  = threadIdx.x;
    const int lane = tid & 63, wid = tid >> 6;
    const int wr = wid >> 1, wc = wid & 1;
    const int g  = lane >> 4;
    const int mrow = wr * 64 + (lane & 15);
    const int nrow = wc * 64 + (lane & 15);

    const u16* Ab = A + (size_t)rowTile * 128 * 256;
    const size_t woff = (size_t)colTile * 128 * 256;

    const int cq0 = colTile * 128 + wr * 64 + ((lane >> 4) << 2);
    const int r0  = rowTile * 128 + wc * 64 + (lane & 15);

    f32x4 acc[4][4];

    // ---- slot 0: KSW fused with swl dot ----
    proj_core(Ab, Wt_ksw + woff, tA, tW, tid, mrow, nrow, g, acc);
    {
        const int hbase = (colTile * 128 + wr * 64) >> 5;  // 2 heads/wave
#pragma unroll
        for (int n = 0; n < 4; ++n) {
            const int r = r0 + n * 16;
            const int ii = r % LRES;
            float s0 = 0.f, s1 = 0.f;
#pragma unroll
            for (int m = 0; m < 4; ++m) {
                const int c = cq0 + m * 16;
                const float4 b4 = *(const float4*)(bias_ksw + c);
                const float4 q4 = *(const float4*)(qsw + (size_t)ii * 256 + c);
                const f32x4 a = acc[m][n];
                const float part = (a[0] + b4.x) * q4.x + (a[1] + b4.y) * q4.y
                                 + (a[2] + b4.z) * q4.z + (a[3] + b4.w) * q4.w;
                if (m < 2) s0 += part; else s1 += part;
            }
            s0 += __shfl_xor(s0, 16, 64); s0 += __shfl_xor(s0, 32, 64);
            s1 += __shfl_xor(s1, 16, 64); s1 += __shfl_xor(s1, 32, 64);
            if (lane < 16) {
                swl[(size_t)r * 8 + hbase]     = s0;
                swl[(size_t)r * 8 + hbase + 1] = s1;
            }
        }
    }

    // ---- slot 1: KT ----
    proj_core(Ab, Wt_k + woff, tA, tW, tid, mrow, nrow, g, acc);
#pragma unroll
    for (int m = 0; m < 4; ++m) {
        const int c = cq0 + m * 16;
        const int h = c >> 5, d = c & 31;
#pragma unroll
        for (int n = 0; n < 4; ++n) {
            const int r = r0 + n * 16;
            const int n_ = r / LRES, ii = r % LRES;
            const f32x4 a = acc[m][n];
            uint2 pk;
            pk.x = pack2(a[0] * SCALE, a[1] * SCALE);
            pk.y = pack2(a[2] * SCALE, a[3] * SCALE);
            *(uint2*)(outKT + (size_t)h * 3145728
                      + (size_t)ii * 8192 + n_ * 32 + d) = pk;
        }
    }

    // ---- slot 2: VT (transposed store) ----
    proj_core(Ab, Wt_v + woff, tA, tW, tid, mrow, nrow, g, acc);
#pragma unroll
    for (int m = 0; m < 4; ++m) {
        const int c = cq0 + m * 16;
        const int h = c >> 5, d = c & 31;
#pragma unroll
        for (int n = 0; n < 4; ++n) {
            const int r = r0 + n * 16;
            const int n_ = r / LRES, ii = r % LRES;
            const f32x4 a = acc[m][n];
            u16* o = outVT + (size_t)h * 3145728
                   + (size_t)(n_ * 32 + d) * 384 + ii;
            o[0]    = f2bf(a[0]);
            o[384]  = f2bf(a[1]);
            o[768]  = f2bf(a[2]);
            o[1152] = f2bf(a[3]);
        }
    }

    // ---- slot 3: GATE ----
    proj_core(Ab, Wt_g + woff, tA, tW, tid, mrow, nrow, g, acc);
#pragma unroll
    for (int m = 0; m < 4; ++m) {
        const int c = cq0 + m * 16;
        const float4 b4 = *(const float4*)(bias_g + c);
#pragma unroll
        for (int n = 0; n < 4; ++n) {
            const int r = r0 + n * 16;
            const f32x4 a = acc[m][n];
            const float f0 = 1.f / (1.f + __expf(-(a[0] + b4.x)));
            const float f1 = 1.f / (1.f + __expf(-(a[1] + b4.y)));
            const float f2 = 1.f / (1.f + __expf(-(a[2] + b4.z)));
            const float f3 = 1.f / (1.f + __expf(-(a[3] + b4.w)));
            uint2 pk;
            pk.x = pack2(f0, f1);
            pk.y = pack2(f2, f3);
            *(uint2*)(outGATE + (size_t)r * 256 + c) = pk;
        }
    }
}

// =====================================================================
// K1'b (MFMA, single): QT (needs seqw) and OUT (final, fp32).
// =====================================================================
enum { PROJ_QT = 1, PROJ_OUT = 5 };

__global__ __launch_bounds__(256) void proj_mfma(
    const u16* __restrict__ A, const u16* __restrict__ Wt,
    const float* __restrict__ bias, const float* __restrict__ seqw,
    void* __restrict__ out, int mode)
{
    __shared__ u16 tA[128 * 64];
    __shared__ u16 tW[128 * 64];

    int wg = (blockIdx.x & 7) * 192 + (blockIdx.x >> 3);
    const int rowTile = wg >> 1;
    const int colTile = wg & 1;

    const int tid  = threadIdx.x;
    const int lane = tid & 63, wid = tid >> 6;
    const int wr = wid >> 1, wc = wid & 1;
    const int g  = lane >> 4;
    const int mrow = wr * 64 + (lane & 15);
    const int nrow = wc * 64 + (lane & 15);

    f32x4 acc[4][4];
    proj_core(A + (size_t)rowTile * 128 * 256, Wt + (size_t)colTile * 128 * 256,
              tA, tW, tid, mrow, nrow, g, acc);

    const int cq0 = colTile * 128 + wr * 64 + ((lane >> 4) << 2);
    const int r0  = rowTile * 128 + wc * 64 + (lane & 15);

#pragma unroll
    for (int m = 0; m < 4; ++m) {
        const int c = cq0 + m * 16;
#pragma unroll
        for (int n = 0; n < 4; ++n) {
            const int r = r0 + n * 16;
            const f32x4 a = acc[m][n];
            if (mode == PROJ_QT) {
                const int h = c >> 5, d = c & 31;
                const int n_ = r / LRES, ii = r % LRES;
                const float mult = seqw[(size_t)r * NH + h];
                uint2 pk;
                pk.x = pack2(a[0] * mult, a[1] * mult);
                pk.y = pack2(a[2] * mult, a[3] * mult);
                *(uint2*)((u16*)out + (size_t)h * 3145728
                          + (size_t)ii * 8192 + n_ * 32 + d) = pk;
            } else { // PROJ_OUT: fp32 + bias
                float* o = (float*)out + (size_t)r * 256 + c;
                o[0] = a[0] + bias[c];
                o[1] = a[1] + bias[c + 1];
                o[2] = a[2] + bias[c + 2];
                o[3] = a[3] + bias[c + 3];
            }
        }
    }
}

// =====================================================================
// K5 (MFMA): part[kc][h][i][j] = sum_{k in kc slice} Q_h[i,k]*K_h[j,k]
// =====================================================================
__global__ __launch_bounds__(256) void gemm_logits_mfma(
    const u16* __restrict__ qT, const u16* __restrict__ kT,
    float* __restrict__ part)
{
    __shared__ u16 tQ[128 * 64];
    __shared__ u16 tK[128 * 64];

    int wg = (blockIdx.x & 7) * 36 + (blockIdx.x >> 3);
    const int gsel = wg / 9;
    const int t    = wg % 9;
    const int h  = gsel >> 2, kc = gsel & 3;
    const int bi = t / 3, bj = t % 3;

    const u16* Q = qT + (size_t)h * 3145728 + (size_t)bi * 128 * 8192;
    const u16* K = kT + (size_t)h * 3145728 + (size_t)bj * 128 * 8192;

    const int tid  = threadIdx.x;
    const int lane = tid & 63, wid = tid >> 6;
    const int wr = wid >> 1, wc = wid & 1;
    const int g  = lane >> 4;
    const int mrow = wr * 64 + (lane & 15);
    const int nrow = wc * 64 + (lane & 15);

    f32x4 acc[4][4];
#pragma unroll
    for (int m = 0; m < 4; ++m)
#pragma unroll
        for (int n = 0; n < 4; ++n) {
            f32x4 z = {0.f, 0.f, 0.f, 0.f};
            acc[m][n] = z;
        }

    const int k0beg = kc * 2048, k0end = k0beg + 2048;
    for (int k0 = k0beg; k0 < k0end; k0 += 64) {
        stage128x64(Q + k0, 8192, tQ, tid);
        stage128x64(K + k0, 8192, tK, tid);
        __syncthreads();
#pragma unroll
        for (int ks = 0; ks < 2; ++ks) {
            bf16x8 kf[4], qf[4];
#pragma unroll
            for (int m = 0; m < 4; ++m) kf[m] = frag_read(tK, mrow + m * 16, ks * 4 + g);
#pragma unroll
            for (int n = 0; n < 4; ++n) qf[n] = frag_read(tQ, nrow + n * 16, ks * 4 + g);
#pragma unroll
            for (int m = 0; m < 4; ++m)
#pragma unroll
                for (int n = 0; n < 4; ++n)
                    acc[m][n] = __builtin_amdgcn_mfma_f32_16x16x32_bf16(
                        kf[m], qf[n], acc[m][n], 0, 0, 0);
        }
        __syncthreads();
    }

    float* dst = part + (size_t)kc * 1179648 + (size_t)h * 147456;
    const int gj_base = bj * 128 + wr * 64 + ((lane >> 4) << 2);
    const int gi_base = bi * 128 + wc * 64 + (lane & 15);
#pragma unroll
    for (int m = 0; m < 4; ++m)
#pragma unroll
        for (int n = 0; n < 4; ++n) {
            const int gi = gi_base + n * 16;
            const int gj = gj_base + m * 16;
            *(f32x4*)(dst + (size_t)gi * 384 + gj) = acc[m][n];
        }
}

// =====================================================================
// K6: attn[h,i,:] = softmax_j( sum_kc part[kc,h,i,:] + biasH[i,:,h] )
// =====================================================================
__global__ __launch_bounds__(256) void softmax_j_k(
    const float* __restrict__ part, const float* __restrict__ biasH,
    u16* __restrict__ attnB)
{
    const int row = blockIdx.x * 4 + (threadIdx.x >> 6);  // h*384+i
    const int lane = threadIdx.x & 63;
    const int h = row / LRES, i = row % LRES;
    const float* p = part + (size_t)h * 147456 + (size_t)i * 384;
    const float* bh = biasH + (size_t)i * 3072 + h;
    float v[6];
#pragma unroll
    for (int t = 0; t < 6; ++t) {
        const int j = t * 64 + lane;
        v[t] = p[j] + p[j + 1179648] + p[j + 2359296] + p[j + 3538944]
             + bh[(size_t)j * 8];
    }
    float mx = v[0];
#pragma unroll
    for (int t = 1; t < 6; ++t) mx = fmaxf(mx, v[t]);
    mx = wred_max(mx);
    float e[6], s = 0.f;
#pragma unroll
    for (int t = 0; t < 6; ++t) { e[t] = __expf(v[t] - mx); s += e[t]; }
    s = wred_sum(s);
    const float inv = 1.f / s;
    u16* ab = attnB + (size_t)h * 147456 + (size_t)i * 384;
#pragma unroll
    for (int t = 0; t < 6; ++t) ab[t * 64 + lane] = f2bf(e[t] * inv);
}

// =====================================================================
// K7 (MFMA): per head O_h = attn_h @ V_h via vTT; gate IN PLACE.
// =====================================================================
__global__ __launch_bounds__(256) void gemm_out_mfma(
    const u16* __restrict__ attnB, const u16* __restrict__ vTT,
    u16* gate_io)
{
    __shared__ u16 tV[128 * 64];
    __shared__ u16 tA[128 * 64];

    int wg = (blockIdx.x & 7) * 192 + (blockIdx.x >> 3);
    const int h  = wg / 192;
    const int r  = wg % 192;
    const int bn = r / 3;
    const int bi = r % 3;

    const u16* A = attnB + (size_t)h * 147456 + (size_t)bi * 128 * 384;
    const u16* V = vTT   + (size_t)h * 3145728 + (size_t)bn * 128 * 384;

    const int tid  = threadIdx.x;
    const int lane = tid & 63, wid = tid >> 6;
    const int wr = wid >> 1, wc = wid & 1;
    const int g  = lane >> 4;
    const int mrow = wr * 64 + (lane & 15);
    const int nrow = wc * 64 + (lane & 15);

    f32x4 acc[4][4];
#pragma unroll
    for (int m = 0; m < 4; ++m)
#pragma unroll
        for (int n = 0; n < 4; ++n) {
            f32x4 z = {0.f, 0.f, 0.f, 0.f};
            acc[m][n] = z;
        }

    for (int j0 = 0; j0 < 384; j0 += 64) {
        stage128x64(V + j0, 384, tV, tid);
        stage128x64(A + j0, 384, tA, tid);
        __syncthreads();
#pragma unroll
        for (int ks = 0; ks < 2; ++ks) {
            bf16x8 vf[4], af[4];
#pragma unroll
            for (int m = 0; m < 4; ++m) vf[m] = frag_read(tV, mrow + m * 16, ks * 4 + g);
#pragma unroll
            for (int n = 0; n < 4; ++n) af[n] = frag_read(tA, nrow + n * 16, ks * 4 + g);
#pragma unroll
            for (int m = 0; m < 4; ++m)
#pragma unroll
                for (int n = 0; n < 4; ++n)
                    acc[m][n] = __builtin_amdgcn_mfma_f32_16x16x32_bf16(
                        vf[m], af[n], acc[m][n], 0, 0, 0);
        }
        __syncthreads();
    }

    const int nd_base = bn * 128 + wr * 64 + ((lane >> 4) << 2);
    const int i_base  = bi * 128 + wc * 64 + (lane & 15);
#pragma unroll
    for (int m = 0; m < 4; ++m) {
        const int nd = nd_base + m * 16;
        const int nseq = nd >> 5, d = nd & 31;
#pragma unroll
        for (int n = 0; n < 4; ++n) {
            const int gi = i_base + n * 16;
            const size_t addr = ((size_t)(nseq * LRES + gi)) * 256 + h * 32 + d;
            uint2 g2 = *(const uint2*)(gate_io + addr);
            float gf[4];
            unpack2(g2.x, gf[0], gf[1]);
            unpack2(g2.y, gf[2], gf[3]);
            const f32x4 a = acc[m][n];
            uint2 pk;
            pk.x = pack2(a[0] * gf[0], a[1] * gf[1]);
            pk.y = pack2(a[2] * gf[2], a[3] * gf[3]);
            *(uint2*)(gate_io + addr) = pk;
        }
    }
}

// =====================================================================
// launcher
// =====================================================================
extern "C" void kernel_launch(void* const* d_in, const int* in_sizes, int n_in,
                              void* d_out, int out_size, void* d_ws, size_t ws_size,
                              hipStream_t stream)
{
    const float* msa       = (const float*)d_in[0];
    const float* pair      = (const float*)d_in[1];
    const float* ln_msa_g  = (const float*)d_in[2];
    const float* ln_msa_b  = (const float*)d_in[3];
    const float* ln_pair_g = (const float*)d_in[4];
    const float* ln_pair_b = (const float*)d_in[5];
    const float* Wq_sw     = (const float*)d_in[6];
    const float* bq_sw     = (const float*)d_in[7];
    const float* Wk_sw     = (const float*)d_in[8];
    const float* bk_sw     = (const float*)d_in[9];
    const float* Wq        = (const float*)d_in[10];
    const float* Wk        = (const float*)d_in[11];
    const float* Wv        = (const float*)d_in[12];
    const float* Wb        = (const float*)d_in[13];
    const float* Wg        = (const float*)d_in[14];
    const float* bg        = (const float*)d_in[15];
    const float* Wo        = (const float*)d_in[16];
    const float* bo        = (const float*)d_in[17];
    float* out = (float*)d_out;   // reference output dtype: float32

    char* ws = (char*)d_ws;
    // Big bf16 buffers (all 50331648 B):
    u16*   B0 = (u16*)(ws + 0);            // qT
    u16*   B1 = (u16*)(ws + 50331648);     // kT
    u16*   B2 = (u16*)(ws + 100663296);    // vTT
    u16*   B3 = (u16*)(ws + 150994944);    // gate -> a2 (in place)
    u16*   lnA = (u16*)(ws + 201326592);   // 50331648 B; DEAD after QT proj
    // Overlays inside lnA region (all written/read after lnA's death):
    float* part  = (float*)(ws + 201326592);             // 18874368 B
    u16*   attnB = (u16*)(ws + 201326592 + 18874368);    // 2359296 B
    float* biasH = (float*)(ws + 201326592 + 21233664);  // 4718592 B
    // Small persistent buffers after lnA:
    float* stats = (float*)(ws + 251658240);  // 786432 B
    float* qsw   = (float*)(ws + 252444672);  // 393216 B
    float* swl   = (float*)(ws + 252837888);  // 3145728 B
    u16*   WtAll = (u16*)(ws + 255983616);    // 786432 B
    float* Wp    = (float*)(ws + 256770048);  // 4096 B
    float* AB    = (float*)(ws + 256774144);  // 64 B
    // total: 256774208 B (~245 MiB)

    u16* Wt_ksw = WtAll;
    u16* Wt_q   = WtAll + 65536;
    u16* Wt_k   = WtAll + 131072;
    u16* Wt_v   = WtAll + 196608;
    u16* Wt_g   = WtAll + 262144;
    u16* Wt_o   = WtAll + 327680;

    // 1. LN(msa) -> bf16 lnA + stats
    ln_msa_k<<<NL / 4, 256, 0, stream>>>(msa, ln_msa_g, ln_msa_b, lnA, stats);
    // 1b. weights -> bf16 transposed
    wconv_k<<<96, 256, 0, stream>>>(Wk_sw, Wq, Wk, Wv, Wg, Wo, WtAll);
    // 1c. pair-bias weight prep
    wbprep_k<<<1, 128, 0, stream>>>(ln_pair_g, ln_pair_b, Wb, Wp, AB);
    // 2. qsw = (LN(msa[0]) @ Wq_sw + bq_sw) * SCALE (fp32, tiny)
    gemm_ln_k<<<dim3(LRES / 64, 2), 256, 0, stream>>>(
        msa, 0, stats, ln_msa_g, ln_msa_b, Wq_sw, bq_sw, qsw, nullptr, 1);
    // 3. fused 4-projection pass: swl (KSW·qsw dot), kT, vTT, gate
    proj4_mfma<<<1536, 256, 0, stream>>>(
        lnA, Wt_ksw, Wt_k, Wt_v, Wt_g, bk_sw, bg, qsw, swl, B1, B2, B3);
    // 4. softmax over n -> seq_weight (in place)
    softmax_n_k<<<LRES * NH / 4, 256, 0, stream>>>(swl);
    // 5. qT = lnA @ Wq, x seq_weight -> B0   (last reader of lnA)
    proj_mfma<<<1536, 256, 0, stream>>>(lnA, Wt_q, nullptr, swl, B0, PROJ_QT);
    // 6. pair bias -> biasH (overlays dead lnA)
    pair_bias_k<<<LRES * LRES / 32, 256, 0, stream>>>(pair, Wp, AB, biasH);
    // 7. logits split-K partials (MFMA) -> part (overlays dead lnA)
    gemm_logits_mfma<<<288, 256, 0, stream>>>(B0, B1, part);
    // 8. softmax over j -> attn bf16
    softmax_j_k<<<NH * LRES / 4, 256, 0, stream>>>(part, biasH, attnB);
    // 9. attn @ V (MFMA), gate applied IN PLACE in B3
    gemm_out_mfma<<<1536, 256, 0, stream>>>(attnB, B2, B3);
    // 10. out = a2 @ Wo + bo -> fp32 out
    proj_mfma<<<1536, 256, 0, stream>>>(B3, Wt_o, bo, nullptr, out, PROJ_OUT);
}

// Round 6
// 605.302 us; speedup vs baseline: 1.0952x; 1.0952x over previous
//
#include <hip/hip_runtime.h>
#include <stdint.h>

#define NSEQ 256
#define LRES 384
#define NH   8
#define NL   (NSEQ*LRES)              // 98304 msa rows
#define SCALE 0.17677669529663687f    // 1/sqrt(32)

typedef unsigned short u16;
typedef unsigned int   u32;
typedef short bf16x8 __attribute__((ext_vector_type(8)));
typedef float f32x4  __attribute__((ext_vector_type(4)));

// ---------- bf16 helpers ----------
__device__ __forceinline__ u16 f2bf(float f) {
    u32 x = __float_as_uint(f);
    return (u16)((x + 0x7fffu + ((x >> 16) & 1u)) >> 16);
}
__device__ __forceinline__ u32 pack2(float a, float b) {
    u32 xa = __float_as_uint(a);
    u32 xb = __float_as_uint(b);
    xa = (xa + 0x7fffu + ((xa >> 16) & 1u)) >> 16;
    xb = ((xb + 0x7fffu + ((xb >> 16) & 1u)) >> 16) << 16;
    return xa | xb;
}
__device__ __forceinline__ uint4 pack8(const float f[8]) {
    uint4 r;
    r.x = pack2(f[0], f[1]); r.y = pack2(f[2], f[3]);
    r.z = pack2(f[4], f[5]); r.w = pack2(f[6], f[7]);
    return r;
}
__device__ __forceinline__ void unpack2(u32 u, float& f0, float& f1) {
    f0 = __uint_as_float((u & 0xffffu) << 16);
    f1 = __uint_as_float(u & 0xffff0000u);
}
__device__ __forceinline__ void unpack8(uint4 p, float f[8]) {
    unpack2(p.x, f[0], f[1]);
    unpack2(p.y, f[2], f[3]);
    unpack2(p.z, f[4], f[5]);
    unpack2(p.w, f[6], f[7]);
}

// ---------- wave-64 reductions ----------
__device__ __forceinline__ float wred_sum(float v) {
#pragma unroll
    for (int o = 32; o > 0; o >>= 1) v += __shfl_xor(v, o, 64);
    return v;
}
__device__ __forceinline__ float wred_max(float v) {
#pragma unroll
    for (int o = 32; o > 0; o >>= 1) v = fmaxf(v, __shfl_xor(v, o, 64));
    return v;
}

// =====================================================================
// K0: fused LN of msa -> bf16 lnA (98304x256), + per-row stats out.
// =====================================================================
__global__ __launch_bounds__(256) void ln_msa_k(
    const float* __restrict__ x, const float* __restrict__ g,
    const float* __restrict__ b, u16* __restrict__ lnA,
    float* __restrict__ stats)
{
    const int lane = threadIdx.x & 63;
    const int row = blockIdx.x * 4 + (threadIdx.x >> 6);
    const size_t base = (size_t)row * 256 + lane * 4;
    float4 v = *(const float4*)(x + base);
    float s  = wred_sum(v.x + v.y + v.z + v.w);
    float sq = wred_sum(v.x*v.x + v.y*v.y + v.z*v.z + v.w*v.w);
    const float mu  = s * (1.f / 256.f);
    const float var = sq * (1.f / 256.f) - mu * mu;
    const float rs  = rsqrtf(var + 1e-5f);
    if (lane == 0) {
        stats[(size_t)row * 2]     = mu;
        stats[(size_t)row * 2 + 1] = rs;
    }
    float4 gg = *(const float4*)(g + lane * 4);
    float4 bb = *(const float4*)(b + lane * 4);
    float f0 = (v.x - mu) * rs * gg.x + bb.x;
    float f1 = (v.y - mu) * rs * gg.y + bb.y;
    float f2 = (v.z - mu) * rs * gg.z + bb.z;
    float f3 = (v.w - mu) * rs * gg.w + bb.w;
    uint2 pk;
    pk.x = pack2(f0, f1);
    pk.y = pack2(f2, f3);
    *(uint2*)(lnA + base) = pk;
}

// =====================================================================
// K0b: transpose+convert 6 weight matrices (256x256 fp32, [k][c]) into
// WtAll (6 x 256 x 256 bf16, [c][k]). 64x64 LDS-tiled. 96 blocks.
// Order: slot weights first (ksw, k, v, g), then q, o.
// =====================================================================
__global__ __launch_bounds__(256) void wconv_k(
    const float* __restrict__ W0, const float* __restrict__ W1,
    const float* __restrict__ W2, const float* __restrict__ W3,
    const float* __restrict__ W4, const float* __restrict__ W5,
    u16* __restrict__ outAll)
{
    const float* Wsrc[6] = {W0, W1, W2, W3, W4, W5};
    const int widx = blockIdx.x >> 4;
    const int tile = blockIdx.x & 15;
    const int kt = tile >> 2, ct = tile & 3;
    const float* W = Wsrc[widx];
    __shared__ float ts[64][65];
    const int r  = threadIdx.x >> 2;     // 0..63
    const int cg = threadIdx.x & 3;      // 16-col group
#pragma unroll
    for (int jj = 0; jj < 4; ++jj) {
        float4 v = *(const float4*)(W + (size_t)(kt * 64 + r) * 256
                                      + ct * 64 + cg * 16 + jj * 4);
        ts[r][cg * 16 + jj * 4 + 0] = v.x;
        ts[r][cg * 16 + jj * 4 + 1] = v.y;
        ts[r][cg * 16 + jj * 4 + 2] = v.z;
        ts[r][cg * 16 + jj * 4 + 3] = v.w;
    }
    __syncthreads();
    float lo[8], hi[8];
#pragma unroll
    for (int j = 0; j < 8; ++j) lo[j] = ts[cg * 16 + j][r];
#pragma unroll
    for (int j = 0; j < 8; ++j) hi[j] = ts[cg * 16 + 8 + j][r];
    u16* o = outAll + (size_t)widx * 65536 + (size_t)(ct * 64 + r) * 256
           + kt * 64 + cg * 16;
    *(uint4*)(o)     = pack8(lo);
    *(uint4*)(o + 8) = pack8(hi);
}

// =====================================================================
// K0c: fold ln_pair_g into Wb -> Wp[c][h] = g_c*Wb[c][h] (fp32), and
// AB[0..7]=A[h]=sum g_c Wb[c][h], AB[8..15]=B[h]=sum b_c Wb[c][h].
// =====================================================================
__global__ __launch_bounds__(128) void wbprep_k(
    const float* __restrict__ g, const float* __restrict__ b,
    const float* __restrict__ Wb, float* __restrict__ Wp,
    float* __restrict__ AB)
{
    __shared__ float ps[128][8];
    __shared__ float pb[128][8];
    const int c = threadIdx.x;
    const float gc = g[c], bc = b[c];
    float4 w0 = *(const float4*)(Wb + (size_t)c * 8);
    float4 w1 = *(const float4*)(Wb + (size_t)c * 8 + 4);
    const float wraw[8] = {w0.x, w0.y, w0.z, w0.w, w1.x, w1.y, w1.z, w1.w};
    float wp[8];
#pragma unroll
    for (int h = 0; h < 8; ++h) {
        wp[h] = wraw[h] * gc;
        ps[c][h] = wp[h];
        pb[c][h] = wraw[h] * bc;
    }
    *(float4*)(Wp + (size_t)c * 8)     = make_float4(wp[0], wp[1], wp[2], wp[3]);
    *(float4*)(Wp + (size_t)c * 8 + 4) = make_float4(wp[4], wp[5], wp[6], wp[7]);
    __syncthreads();
    if (c < 8) {
        float a = 0.f;
        for (int j = 0; j < 128; ++j) a += ps[j][c];
        AB[c] = a;
    } else if (c < 16) {
        const int h = c - 8;
        float a = 0.f;
        for (int j = 0; j < 128; ++j) a += pb[j][h];
        AB[8 + h] = a;
    }
}

// =====================================================================
// K1 (legacy fp32 path, QSW only): qsw = (LN(msa[0]) @ W + b) * SCALE.
// =====================================================================
__global__ __launch_bounds__(256) void gemm_ln_k(
    const void* __restrict__ Av, int a_bf16,
    const float* __restrict__ stats,
    const float* __restrict__ lng, const float* __restrict__ lnb,
    const float* __restrict__ W, const float* __restrict__ bias,
    void* __restrict__ out, const float* __restrict__ seqw, int mode)
{
    __shared__ float As_t[32][68];   // [k][row]
    __shared__ float Ws[32][132];    // [k][col]
    __shared__ float gs[256], bs[256];
    const int tid = threadIdx.x;
    const int bx = blockIdx.y;       // column half
    const int by = blockIdx.x;       // row tile
    const int tx = tid & 15, ty = tid >> 4;
    const int ar = tid >> 2, acg = tid & 3;
    const int wr = tid >> 3, wcg = tid & 7;
    const bool do_ln = (stats != nullptr);

    if (do_ln) { gs[tid] = lng[tid]; bs[tid] = lnb[tid]; }
    __syncthreads();

    const int arow_idx = by * 64 + ar;
    float mu = 0.f, rsg = 0.f;
    if (do_ln) {
        mu  = stats[(size_t)arow_idx * 2];
        rsg = stats[(size_t)arow_idx * 2 + 1];
    }

    float acc[4][8];
#pragma unroll
    for (int i = 0; i < 4; ++i)
#pragma unroll
        for (int j = 0; j < 8; ++j) acc[i][j] = 0.f;

    const size_t arow = (size_t)arow_idx * 256 + acg * 8;

    for (int kk = 0; kk < 256; kk += 32) {
        float af[8];
        if (a_bf16) {
            uint4 a8 = *(const uint4*)((const u16*)Av + arow + kk);
            unpack8(a8, af);
        } else {
            float4 x0 = *(const float4*)((const float*)Av + arow + kk);
            float4 x1 = *(const float4*)((const float*)Av + arow + kk + 4);
            af[0] = x0.x; af[1] = x0.y; af[2] = x0.z; af[3] = x0.w;
            af[4] = x1.x; af[5] = x1.y; af[6] = x1.z; af[7] = x1.w;
        }
        const float* wrow = W + (size_t)(kk + wr) * 256 + bx * 128 + wcg * 16;
        float4 w0 = *(const float4*)(wrow);
        float4 w1 = *(const float4*)(wrow + 4);
        float4 w2 = *(const float4*)(wrow + 8);
        float4 w3 = *(const float4*)(wrow + 12);
        if (do_ln) {
#pragma unroll
            for (int j = 0; j < 8; ++j) {
                const int k = kk + acg * 8 + j;
                af[j] = (af[j] - mu) * rsg * gs[k] + bs[k];
            }
        }
        __syncthreads();
#pragma unroll
        for (int j = 0; j < 8; ++j) As_t[acg * 8 + j][ar] = af[j];
        float* wsrow = &Ws[wr][wcg * 16];
        *(float4*)(wsrow)      = w0;
        *(float4*)(wsrow + 4)  = w1;
        *(float4*)(wsrow + 8)  = w2;
        *(float4*)(wsrow + 12) = w3;
        __syncthreads();
#pragma unroll 8
        for (int k = 0; k < 32; ++k) {
            const float4 a  = *(const float4*)&As_t[k][ty * 4];
            const float4 b0 = *(const float4*)&Ws[k][tx * 8];
            const float4 b1 = *(const float4*)&Ws[k][tx * 8 + 4];
            const float av[4] = {a.x, a.y, a.z, a.w};
            const float bv[8] = {b0.x, b0.y, b0.z, b0.w, b1.x, b1.y, b1.z, b1.w};
#pragma unroll
            for (int i = 0; i < 4; ++i)
#pragma unroll
                for (int j = 0; j < 8; ++j)
                    acc[i][j] = fmaf(av[i], bv[j], acc[i][j]);
        }
    }

    const int gc0 = bx * 128 + tx * 8;
    float bias8[8];
#pragma unroll
    for (int j = 0; j < 8; ++j) bias8[j] = bias[gc0 + j];

    float* o = (float*)out;
#pragma unroll
    for (int i = 0; i < 4; ++i) {
        const size_t gr = (size_t)by * 64 + ty * 4 + i;
#pragma unroll
        for (int j = 0; j < 8; ++j)
            o[gr * 256 + gc0 + j] = (acc[i][j] + bias8[j]) * SCALE;
    }
}

// =====================================================================
// K3: softmax over n (stride 3072) per (i,h) column. Wave per column.
// =====================================================================
__global__ __launch_bounds__(256) void softmax_n_k(float* __restrict__ swl)
{
    const int col = blockIdx.x * 4 + (threadIdx.x >> 6);  // i*8+h
    const int lane = threadIdx.x & 63;
    float* base = swl + col;
    float v[4];
#pragma unroll
    for (int t = 0; t < 4; ++t) v[t] = base[(size_t)(lane * 4 + t) * 3072];
    float mx = wred_max(fmaxf(fmaxf(v[0], v[1]), fmaxf(v[2], v[3])));
    float e[4], s = 0.f;
#pragma unroll
    for (int t = 0; t < 4; ++t) { e[t] = __expf(v[t] - mx); s += e[t]; }
    s = wred_sum(s);
    const float inv = 1.f / s;
#pragma unroll
    for (int t = 0; t < 4; ++t) base[(size_t)(lane * 4 + t) * 3072] = e[t] * inv;
}

// =====================================================================
// K4: biasH[(i*384+j)*8+h] = rs*dot(x, Wp[:,h]) - rs*mu*A[h] + B[h].
// 8 pairs/wave; XOR-aligned head accumulation.
// =====================================================================
__global__ __launch_bounds__(256) void pair_bias_k(
    const float* __restrict__ pairX, const float* __restrict__ Wp,
    const float* __restrict__ AB, float* __restrict__ biasH)
{
    __shared__ float ws[128][8];
    __shared__ float As[8], Bs[8];
    const int tid = threadIdx.x;
    {
        float4 w4 = *(const float4*)(Wp + tid * 4);
        *(float4*)(&ws[tid >> 1][(tid & 1) * 4]) = w4;
    }
    if (tid < 8)       As[tid] = AB[tid];
    else if (tid < 16) Bs[tid - 8] = AB[tid];
    __syncthreads();

    const int lane = tid & 63;
    const int p  = lane >> 3;
    const int cg = lane & 7;
    const size_t pb = (size_t)blockIdx.x * 32 + (tid >> 6) * 8 + p;
    const float* src = pairX + pb * 128 + cg * 16;
    float x[16];
    *(float4*)(x)      = *(const float4*)(src);
    *(float4*)(x + 4)  = *(const float4*)(src + 4);
    *(float4*)(x + 8)  = *(const float4*)(src + 8);
    *(float4*)(x + 12) = *(const float4*)(src + 12);

    float s = 0.f, sq = 0.f;
#pragma unroll
    for (int j = 0; j < 16; ++j) { s += x[j]; sq += x[j] * x[j]; }
#pragma unroll
    for (int o = 1; o <= 4; o <<= 1) {
        s  += __shfl_xor(s, o, 64);
        sq += __shfl_xor(sq, o, 64);
    }
    const float mu  = s * (1.f / 128.f);
    const float var = sq * (1.f / 128.f) - mu * mu;
    const float rs  = rsqrtf(var + 1e-5f);

    float acc[8];
#pragma unroll
    for (int hh = 0; hh < 8; ++hh) {
        const int h = hh ^ cg;
        float a = 0.f;
#pragma unroll
        for (int j = 0; j < 16; ++j) a += x[j] * ws[cg * 16 + j][h];
        acc[hh] = a;
    }
#pragma unroll
    for (int o = 1; o <= 4; o <<= 1) {
        float nv[8];
#pragma unroll
        for (int hh = 0; hh < 8; ++hh)
            nv[hh] = acc[hh] + __shfl_xor(acc[hh ^ o], o, 64);
#pragma unroll
        for (int hh = 0; hh < 8; ++hh) acc[hh] = nv[hh];
    }
    const float res = rs * acc[0] - rs * mu * As[cg] + Bs[cg];
    biasH[pb * 8 + cg] = res;
}

// =====================================================================
// MFMA tile helpers: [128 rows][64 k] bf16 tile in LDS, XOR-swizzled.
// =====================================================================
__device__ __forceinline__ void stage128x64(
    const u16* __restrict__ src, size_t rowStride, u16* lds, int tid)
{
    const int row   = tid >> 1;          // 128 rows, 2 threads each
    const int cbase = (tid & 1) * 4;     // chunks {0..3} or {4..7}
#pragma unroll
    for (int ch = 0; ch < 4; ++ch) {
        const int cc = cbase + ch;
        const uint4 v = *(const uint4*)(src + (size_t)row * rowStride + cc * 8);
        *(uint4*)(lds + row * 64 + ((cc ^ (row & 7)) * 8)) = v;
    }
}

__device__ __forceinline__ bf16x8 frag_read(const u16* lds, int row, int kchunk)
{
    return *(const bf16x8*)(lds + row * 64 + ((kchunk ^ (row & 7)) * 8));
}

// Shared MFMA core: 128x128 C-tile, K=256 (A and Wt both [row][256] bf16).
__device__ __forceinline__ void proj_core(
    const u16* __restrict__ Ab, const u16* __restrict__ Wb,
    u16* tA, u16* tW, int tid, int mrow, int nrow, int g, f32x4 acc[4][4])
{
#pragma unroll
    for (int m = 0; m < 4; ++m)
#pragma unroll
        for (int n = 0; n < 4; ++n) {
            f32x4 z = {0.f, 0.f, 0.f, 0.f};
            acc[m][n] = z;
        }
    for (int k0 = 0; k0 < 256; k0 += 64) {
        stage128x64(Ab + k0, 256, tA, tid);
        stage128x64(Wb + k0, 256, tW, tid);
        __syncthreads();
#pragma unroll
        for (int ks = 0; ks < 2; ++ks) {
            bf16x8 wf[4], af[4];
#pragma unroll
            for (int m = 0; m < 4; ++m) wf[m] = frag_read(tW, mrow + m * 16, ks * 4 + g);
#pragma unroll
            for (int n = 0; n < 4; ++n) af[n] = frag_read(tA, nrow + n * 16, ks * 4 + g);
#pragma unroll
            for (int m = 0; m < 4; ++m)
#pragma unroll
                for (int n = 0; n < 4; ++n)
                    acc[m][n] = __builtin_amdgcn_mfma_f32_16x16x32_bf16(
                        wf[m], af[n], acc[m][n], 0, 0, 0);
        }
        __syncthreads();
    }
}

// =====================================================================
// K1'a (MFMA, grid-split x4): 6144 blocks. Grid order within XCD chunk:
// [rowTile(768)][slot(4)][colTile(2)] -> 8 consecutive blocks share the
// 64KB A-tile via same-XCD L2. One proj_core + one epilogue per block.
//  slot0: KSW -> fused swl dot (never materializes ksw)
//  slot1: KT  -> kT bf16 [h][i][n*32+d], x SCALE
//  slot2: VT  -> vTT bf16 [h][n*32+d][i]
//  slot3: GATE-> sigmoid(.+bg) bf16 [r][c]
// =====================================================================
__global__ __launch_bounds__(256, 4) void projX_mfma(
    const u16* __restrict__ A, const u16* __restrict__ Wt4,
    const float* __restrict__ bias_ksw, const float* __restrict__ bias_g,
    const float* __restrict__ qsw,
    float* __restrict__ swl, u16* __restrict__ outKT,
    u16* __restrict__ outVT, u16* __restrict__ outGATE)
{
    __shared__ u16 tA[128 * 64];
    __shared__ u16 tW[128 * 64];

    int wg = (blockIdx.x & 7) * 768 + (blockIdx.x >> 3);
    const int rowTile = wg >> 3;         // 0..767
    const int slot    = (wg >> 1) & 3;   // 0..3
    const int colTile = wg & 1;          // 0..1

    const int tid  = threadIdx.x;
    const int lane = tid & 63, wid = tid >> 6;
    const int wr = wid >> 1, wc = wid & 1;
    const int g  = lane >> 4;
    const int mrow = wr * 64 + (lane & 15);
    const int nrow = wc * 64 + (lane & 15);

    const u16* Ab = A + (size_t)rowTile * 128 * 256;
    const u16* Wb = Wt4 + (size_t)slot * 65536 + (size_t)colTile * 128 * 256;

    f32x4 acc[4][4];
    proj_core(Ab, Wb, tA, tW, tid, mrow, nrow, g, acc);

    const int cq0 = colTile * 128 + wr * 64 + ((lane >> 4) << 2);
    const int r0  = rowTile * 128 + wc * 64 + (lane & 15);

    if (slot == 0) {
        // KSW fused with swl dot
        const int hbase = (colTile * 128 + wr * 64) >> 5;  // 2 heads/wave
#pragma unroll
        for (int n = 0; n < 4; ++n) {
            const int r = r0 + n * 16;
            const int ii = r % LRES;
            float s0 = 0.f, s1 = 0.f;
#pragma unroll
            for (int m = 0; m < 4; ++m) {
                const int c = cq0 + m * 16;
                const float4 b4 = *(const float4*)(bias_ksw + c);
                const float4 q4 = *(const float4*)(qsw + (size_t)ii * 256 + c);
                const f32x4 a = acc[m][n];
                const float part = (a[0] + b4.x) * q4.x + (a[1] + b4.y) * q4.y
                                 + (a[2] + b4.z) * q4.z + (a[3] + b4.w) * q4.w;
                if (m < 2) s0 += part; else s1 += part;
            }
            s0 += __shfl_xor(s0, 16, 64); s0 += __shfl_xor(s0, 32, 64);
            s1 += __shfl_xor(s1, 16, 64); s1 += __shfl_xor(s1, 32, 64);
            if (lane < 16) {
                swl[(size_t)r * 8 + hbase]     = s0;
                swl[(size_t)r * 8 + hbase + 1] = s1;
            }
        }
    } else if (slot == 1) {
        // KT
#pragma unroll
        for (int m = 0; m < 4; ++m) {
            const int c = cq0 + m * 16;
            const int h = c >> 5, d = c & 31;
#pragma unroll
            for (int n = 0; n < 4; ++n) {
                const int r = r0 + n * 16;
                const int n_ = r / LRES, ii = r % LRES;
                const f32x4 a = acc[m][n];
                uint2 pk;
                pk.x = pack2(a[0] * SCALE, a[1] * SCALE);
                pk.y = pack2(a[2] * SCALE, a[3] * SCALE);
                *(uint2*)(outKT + (size_t)h * 3145728
                          + (size_t)ii * 8192 + n_ * 32 + d) = pk;
            }
        }
    } else if (slot == 2) {
        // VT (transposed store)
#pragma unroll
        for (int m = 0; m < 4; ++m) {
            const int c = cq0 + m * 16;
            const int h = c >> 5, d = c & 31;
#pragma unroll
            for (int n = 0; n < 4; ++n) {
                const int r = r0 + n * 16;
                const int n_ = r / LRES, ii = r % LRES;
                const f32x4 a = acc[m][n];
                u16* o = outVT + (size_t)h * 3145728
                       + (size_t)(n_ * 32 + d) * 384 + ii;
                o[0]    = f2bf(a[0]);
                o[384]  = f2bf(a[1]);
                o[768]  = f2bf(a[2]);
                o[1152] = f2bf(a[3]);
            }
        }
    } else {
        // GATE
#pragma unroll
        for (int m = 0; m < 4; ++m) {
            const int c = cq0 + m * 16;
            const float4 b4 = *(const float4*)(bias_g + c);
#pragma unroll
            for (int n = 0; n < 4; ++n) {
                const int r = r0 + n * 16;
                const f32x4 a = acc[m][n];
                const float f0 = 1.f / (1.f + __expf(-(a[0] + b4.x)));
                const float f1 = 1.f / (1.f + __expf(-(a[1] + b4.y)));
                const float f2 = 1.f / (1.f + __expf(-(a[2] + b4.z)));
                const float f3 = 1.f / (1.f + __expf(-(a[3] + b4.w)));
                uint2 pk;
                pk.x = pack2(f0, f1);
                pk.y = pack2(f2, f3);
                *(uint2*)(outGATE + (size_t)r * 256 + c) = pk;
            }
        }
    }
}

// =====================================================================
// K1'b (MFMA, single): QT (needs seqw) and OUT (final, fp32).
// =====================================================================
enum { PROJ_QT = 1, PROJ_OUT = 5 };

__global__ __launch_bounds__(256) void proj_mfma(
    const u16* __restrict__ A, const u16* __restrict__ Wt,
    const float* __restrict__ bias, const float* __restrict__ seqw,
    void* __restrict__ out, int mode)
{
    __shared__ u16 tA[128 * 64];
    __shared__ u16 tW[128 * 64];

    int wg = (blockIdx.x & 7) * 192 + (blockIdx.x >> 3);
    const int rowTile = wg >> 1;
    const int colTile = wg & 1;

    const int tid  = threadIdx.x;
    const int lane = tid & 63, wid = tid >> 6;
    const int wr = wid >> 1, wc = wid & 1;
    const int g  = lane >> 4;
    const int mrow = wr * 64 + (lane & 15);
    const int nrow = wc * 64 + (lane & 15);

    f32x4 acc[4][4];
    proj_core(A + (size_t)rowTile * 128 * 256, Wt + (size_t)colTile * 128 * 256,
              tA, tW, tid, mrow, nrow, g, acc);

    const int cq0 = colTile * 128 + wr * 64 + ((lane >> 4) << 2);
    const int r0  = rowTile * 128 + wc * 64 + (lane & 15);

#pragma unroll
    for (int m = 0; m < 4; ++m) {
        const int c = cq0 + m * 16;
#pragma unroll
        for (int n = 0; n < 4; ++n) {
            const int r = r0 + n * 16;
            const f32x4 a = acc[m][n];
            if (mode == PROJ_QT) {
                const int h = c >> 5, d = c & 31;
                const int n_ = r / LRES, ii = r % LRES;
                const float mult = seqw[(size_t)r * NH + h];
                uint2 pk;
                pk.x = pack2(a[0] * mult, a[1] * mult);
                pk.y = pack2(a[2] * mult, a[3] * mult);
                *(uint2*)((u16*)out + (size_t)h * 3145728
                          + (size_t)ii * 8192 + n_ * 32 + d) = pk;
            } else { // PROJ_OUT: fp32 + bias
                float* o = (float*)out + (size_t)r * 256 + c;
                o[0] = a[0] + bias[c];
                o[1] = a[1] + bias[c + 1];
                o[2] = a[2] + bias[c + 2];
                o[3] = a[3] + bias[c + 3];
            }
        }
    }
}

// =====================================================================
// K5 (MFMA): part[kc][h][i][j] = sum_{k in kc slice} Q_h[i,k]*K_h[j,k]
// =====================================================================
__global__ __launch_bounds__(256) void gemm_logits_mfma(
    const u16* __restrict__ qT, const u16* __restrict__ kT,
    float* __restrict__ part)
{
    __shared__ u16 tQ[128 * 64];
    __shared__ u16 tK[128 * 64];

    int wg = (blockIdx.x & 7) * 36 + (blockIdx.x >> 3);
    const int gsel = wg / 9;
    const int t    = wg % 9;
    const int h  = gsel >> 2, kc = gsel & 3;
    const int bi = t / 3, bj = t % 3;

    const u16* Q = qT + (size_t)h * 3145728 + (size_t)bi * 128 * 8192;
    const u16* K = kT + (size_t)h * 3145728 + (size_t)bj * 128 * 8192;

    const int tid  = threadIdx.x;
    const int lane = tid & 63, wid = tid >> 6;
    const int wr = wid >> 1, wc = wid & 1;
    const int g  = lane >> 4;
    const int mrow = wr * 64 + (lane & 15);
    const int nrow = wc * 64 + (lane & 15);

    f32x4 acc[4][4];
#pragma unroll
    for (int m = 0; m < 4; ++m)
#pragma unroll
        for (int n = 0; n < 4; ++n) {
            f32x4 z = {0.f, 0.f, 0.f, 0.f};
            acc[m][n] = z;
        }

    const int k0beg = kc * 2048, k0end = k0beg + 2048;
    for (int k0 = k0beg; k0 < k0end; k0 += 64) {
        stage128x64(Q + k0, 8192, tQ, tid);
        stage128x64(K + k0, 8192, tK, tid);
        __syncthreads();
#pragma unroll
        for (int ks = 0; ks < 2; ++ks) {
            bf16x8 kf[4], qf[4];
#pragma unroll
            for (int m = 0; m < 4; ++m) kf[m] = frag_read(tK, mrow + m * 16, ks * 4 + g);
#pragma unroll
            for (int n = 0; n < 4; ++n) qf[n] = frag_read(tQ, nrow + n * 16, ks * 4 + g);
#pragma unroll
            for (int m = 0; m < 4; ++m)
#pragma unroll
                for (int n = 0; n < 4; ++n)
                    acc[m][n] = __builtin_amdgcn_mfma_f32_16x16x32_bf16(
                        kf[m], qf[n], acc[m][n], 0, 0, 0);
        }
        __syncthreads();
    }

    float* dst = part + (size_t)kc * 1179648 + (size_t)h * 147456;
    const int gj_base = bj * 128 + wr * 64 + ((lane >> 4) << 2);
    const int gi_base = bi * 128 + wc * 64 + (lane & 15);
#pragma unroll
    for (int m = 0; m < 4; ++m)
#pragma unroll
        for (int n = 0; n < 4; ++n) {
            const int gi = gi_base + n * 16;
            const int gj = gj_base + m * 16;
            *(f32x4*)(dst + (size_t)gi * 384 + gj) = acc[m][n];
        }
}

// =====================================================================
// K6: attn[h,i,:] = softmax_j( sum_kc part[kc,h,i,:] + biasH[i,:,h] )
// =====================================================================
__global__ __launch_bounds__(256) void softmax_j_k(
    const float* __restrict__ part, const float* __restrict__ biasH,
    u16* __restrict__ attnB)
{
    const int row = blockIdx.x * 4 + (threadIdx.x >> 6);  // h*384+i
    const int lane = threadIdx.x & 63;
    const int h = row / LRES, i = row % LRES;
    const float* p = part + (size_t)h * 147456 + (size_t)i * 384;
    const float* bh = biasH + (size_t)i * 3072 + h;
    float v[6];
#pragma unroll
    for (int t = 0; t < 6; ++t) {
        const int j = t * 64 + lane;
        v[t] = p[j] + p[j + 1179648] + p[j + 2359296] + p[j + 3538944]
             + bh[(size_t)j * 8];
    }
    float mx = v[0];
#pragma unroll
    for (int t = 1; t < 6; ++t) mx = fmaxf(mx, v[t]);
    mx = wred_max(mx);
    float e[6], s = 0.f;
#pragma unroll
    for (int t = 0; t < 6; ++t) { e[t] = __expf(v[t] - mx); s += e[t]; }
    s = wred_sum(s);
    const float inv = 1.f / s;
    u16* ab = attnB + (size_t)h * 147456 + (size_t)i * 384;
#pragma unroll
    for (int t = 0; t < 6; ++t) ab[t * 64 + lane] = f2bf(e[t] * inv);
}

// =====================================================================
// K7 (MFMA): per head O_h = attn_h @ V_h via vTT; gate IN PLACE.
// =====================================================================
__global__ __launch_bounds__(256) void gemm_out_mfma(
    const u16* __restrict__ attnB, const u16* __restrict__ vTT,
    u16* gate_io)
{
    __shared__ u16 tV[128 * 64];
    __shared__ u16 tA[128 * 64];

    int wg = (blockIdx.x & 7) * 192 + (blockIdx.x >> 3);
    const int h  = wg / 192;
    const int r  = wg % 192;
    const int bn = r / 3;
    const int bi = r % 3;

    const u16* A = attnB + (size_t)h * 147456 + (size_t)bi * 128 * 384;
    const u16* V = vTT   + (size_t)h * 3145728 + (size_t)bn * 128 * 384;

    const int tid  = threadIdx.x;
    const int lane = tid & 63, wid = tid >> 6;
    const int wr = wid >> 1, wc = wid & 1;
    const int g  = lane >> 4;
    const int mrow = wr * 64 + (lane & 15);
    const int nrow = wc * 64 + (lane & 15);

    f32x4 acc[4][4];
#pragma unroll
    for (int m = 0; m < 4; ++m)
#pragma unroll
        for (int n = 0; n < 4; ++n) {
            f32x4 z = {0.f, 0.f, 0.f, 0.f};
            acc[m][n] = z;
        }

    for (int j0 = 0; j0 < 384; j0 += 64) {
        stage128x64(V + j0, 384, tV, tid);
        stage128x64(A + j0, 384, tA, tid);
        __syncthreads();
#pragma unroll
        for (int ks = 0; ks < 2; ++ks) {
            bf16x8 vf[4], af[4];
#pragma unroll
            for (int m = 0; m < 4; ++m) vf[m] = frag_read(tV, mrow + m * 16, ks * 4 + g);
#pragma unroll
            for (int n = 0; n < 4; ++n) af[n] = frag_read(tA, nrow + n * 16, ks * 4 + g);
#pragma unroll
            for (int m = 0; m < 4; ++m)
#pragma unroll
                for (int n = 0; n < 4; ++n)
                    acc[m][n] = __builtin_amdgcn_mfma_f32_16x16x32_bf16(
                        vf[m], af[n], acc[m][n], 0, 0, 0);
        }
        __syncthreads();
    }

    const int nd_base = bn * 128 + wr * 64 + ((lane >> 4) << 2);
    const int i_base  = bi * 128 + wc * 64 + (lane & 15);
#pragma unroll
    for (int m = 0; m < 4; ++m) {
        const int nd = nd_base + m * 16;
        const int nseq = nd >> 5, d = nd & 31;
#pragma unroll
        for (int n = 0; n < 4; ++n) {
            const int gi = i_base + n * 16;
            const size_t addr = ((size_t)(nseq * LRES + gi)) * 256 + h * 32 + d;
            uint2 g2 = *(const uint2*)(gate_io + addr);
            float gf[4];
            unpack2(g2.x, gf[0], gf[1]);
            unpack2(g2.y, gf[2], gf[3]);
            const f32x4 a = acc[m][n];
            uint2 pk;
            pk.x = pack2(a[0] * gf[0], a[1] * gf[1]);
            pk.y = pack2(a[2] * gf[2], a[3] * gf[3]);
            *(uint2*)(gate_io + addr) = pk;
        }
    }
}

// =====================================================================
// launcher
// =====================================================================
extern "C" void kernel_launch(void* const* d_in, const int* in_sizes, int n_in,
                              void* d_out, int out_size, void* d_ws, size_t ws_size,
                              hipStream_t stream)
{
    const float* msa       = (const float*)d_in[0];
    const float* pair      = (const float*)d_in[1];
    const float* ln_msa_g  = (const float*)d_in[2];
    const float* ln_msa_b  = (const float*)d_in[3];
    const float* ln_pair_g = (const float*)d_in[4];
    const float* ln_pair_b = (const float*)d_in[5];
    const float* Wq_sw     = (const float*)d_in[6];
    const float* bq_sw     = (const float*)d_in[7];
    const float* Wk_sw     = (const float*)d_in[8];
    const float* bk_sw     = (const float*)d_in[9];
    const float* Wq        = (const float*)d_in[10];
    const float* Wk        = (const float*)d_in[11];
    const float* Wv        = (const float*)d_in[12];
    const float* Wb        = (const float*)d_in[13];
    const float* Wg        = (const float*)d_in[14];
    const float* bg        = (const float*)d_in[15];
    const float* Wo        = (const float*)d_in[16];
    const float* bo        = (const float*)d_in[17];
    float* out = (float*)d_out;   // reference output dtype: float32

    char* ws = (char*)d_ws;
    // Big bf16 buffers (all 50331648 B):
    u16*   B0 = (u16*)(ws + 0);            // qT
    u16*   B1 = (u16*)(ws + 50331648);     // kT
    u16*   B2 = (u16*)(ws + 100663296);    // vTT
    u16*   B3 = (u16*)(ws + 150994944);    // gate -> a2 (in place)
    u16*   lnA = (u16*)(ws + 201326592);   // 50331648 B; DEAD after QT proj
    // Overlays inside lnA region (all written/read after lnA's death):
    float* part  = (float*)(ws + 201326592);             // 18874368 B
    u16*   attnB = (u16*)(ws + 201326592 + 18874368);    // 2359296 B
    float* biasH = (float*)(ws + 201326592 + 21233664);  // 4718592 B
    // Small persistent buffers after lnA:
    float* stats = (float*)(ws + 251658240);  // 786432 B
    float* qsw   = (float*)(ws + 252444672);  // 393216 B
    float* swl   = (float*)(ws + 252837888);  // 3145728 B
    u16*   WtAll = (u16*)(ws + 255983616);    // 786432 B
    float* Wp    = (float*)(ws + 256770048);  // 4096 B
    float* AB    = (float*)(ws + 256774144);  // 64 B
    // total: 256774208 B (~245 MiB)

    // WtAll slot order: [0]=ksw [1]=k [2]=v [3]=g [4]=q [5]=o
    u16* Wt_q   = WtAll + 4 * 65536;
    u16* Wt_o   = WtAll + 5 * 65536;

    // 1. LN(msa) -> bf16 lnA + stats
    ln_msa_k<<<NL / 4, 256, 0, stream>>>(msa, ln_msa_g, ln_msa_b, lnA, stats);
    // 1b. weights -> bf16 transposed (slot order: ksw, k, v, g, q, o)
    wconv_k<<<96, 256, 0, stream>>>(Wk_sw, Wk, Wv, Wg, Wq, Wo, WtAll);
    // 1c. pair-bias weight prep
    wbprep_k<<<1, 128, 0, stream>>>(ln_pair_g, ln_pair_b, Wb, Wp, AB);
    // 2. qsw = (LN(msa[0]) @ Wq_sw + bq_sw) * SCALE (fp32, tiny)
    gemm_ln_k<<<dim3(LRES / 64, 2), 256, 0, stream>>>(
        msa, 0, stats, ln_msa_g, ln_msa_b, Wq_sw, bq_sw, qsw, nullptr, 1);
    // 3. grid-split 4-projection pass: swl (KSW·qsw dot), kT, vTT, gate
    projX_mfma<<<6144, 256, 0, stream>>>(
        lnA, WtAll, bk_sw, bg, qsw, swl, B1, B2, B3);
    // 4. softmax over n -> seq_weight (in place)
    softmax_n_k<<<LRES * NH / 4, 256, 0, stream>>>(swl);
    // 5. qT = lnA @ Wq, x seq_weight -> B0   (last reader of lnA)
    proj_mfma<<<1536, 256, 0, stream>>>(lnA, Wt_q, nullptr, swl, B0, PROJ_QT);
    // 6. pair bias -> biasH (overlays dead lnA)
    pair_bias_k<<<LRES * LRES / 32, 256, 0, stream>>>(pair, Wp, AB, biasH);
    // 7. logits split-K partials (MFMA) -> part (overlays dead lnA)
    gemm_logits_mfma<<<288, 256, 0, stream>>>(B0, B1, part);
    // 8. softmax over j -> attn bf16
    softmax_j_k<<<NH * LRES / 4, 256, 0, stream>>>(part, biasH, attnB);
    // 9. attn @ V (MFMA), gate applied IN PLACE in B3
    gemm_out_mfma<<<1536, 256, 0, stream>>>(attnB, B2, B3);
    // 10. out = a2 @ Wo + bo -> fp32 out
    proj_mfma<<<1536, 256, 0, stream>>>(B3, Wt_o, bo, nullptr, out, PROJ_OUT);
}